// Round 18
// baseline (67.667 us; speedup 1.0000x reference)
//
#include <hip/hip_runtime.h>
#include <math.h>

#define I_DIM 1024
#define S_DIM 512
#define O_DIM 1024
#define T_DIM 2048
#define B_SZ 4
#define M_ROWS (B_SZ * T_DIM)   // 8192
#define EPSF 1e-6f

// scan chunking: chunk length == GEMM BM (64)
#define CL 64
#define NCH 32   // NCH*CL == T_DIM

typedef _Float16 f16;
typedef __attribute__((ext_vector_type(8))) _Float16 f16x8;
typedef __attribute__((ext_vector_type(2))) _Float16 f16x2;
typedef __attribute__((ext_vector_type(4))) float f32x4;

__device__ __forceinline__ unsigned short f2h_bits(float f) {
    _Float16 h = (_Float16)f;
    return __builtin_bit_cast(unsigned short, h);
}

// async 16B global -> LDS (wave-uniform LDS base + lane*16 -> LINEAR dest only)
__device__ __forceinline__ void load16_lds(const void* g, void* l) {
    __builtin_amdgcn_global_load_lds((const __attribute__((address_space(1))) void*)g,
                                     (__attribute__((address_space(3))) void*)l,
                                     16, 0, 0);
}

// ---------------------------------------------------------------------------
// prep: weight transposes only (~1.5 us).
// ---------------------------------------------------------------------------
__global__ __launch_bounds__(256)
void prep_w(const float* __restrict__ Bmat, const float* __restrict__ dt,
            const float* __restrict__ nw, unsigned short* __restrict__ Bt16,
            const float* __restrict__ Cmat, unsigned short* __restrict__ Ct16) {
    __shared__ float tile[32][33];
    const int t = threadIdx.x;
    const int tx = t & 31, ty = t >> 5;
    const int bx = blockIdx.x;
    if (bx < 512) {
        const int bs = (bx & 15) * 32;   // s block
        const int bi = (bx >> 4) * 32;   // i block
        #pragma unroll
        for (int i = ty; i < 32; i += 8)
            tile[i][tx] = Bmat[(size_t)(bi + i) * S_DIM + bs + tx];
        __syncthreads();
        const float w = nw[bi + tx];
        #pragma unroll
        for (int i = ty; i < 32; i += 8) {
            const int s = bs + i;
            const float dts = 1.0f / (1.0f + expf(-dt[s]));
            Bt16[(size_t)s * I_DIM + bi + tx] = f2h_bits(tile[tx][i] * dts * w);
        }
    } else {
        const int tb = bx - 512;
        const int bo = (tb & 31) * 32;   // o block
        const int bs = (tb >> 5) * 32;   // s block
        #pragma unroll
        for (int i = ty; i < 32; i += 8)
            tile[i][tx] = Cmat[(size_t)(bs + i) * O_DIM + bo + tx];
        __syncthreads();
        #pragma unroll
        for (int i = ty; i < 32; i += 8)
            Ct16[(size_t)(bo + i) * S_DIM + bs + tx] = f2h_bits(tile[tx][i]);
    }
}

// ---------------------------------------------------------------------------
// GEMM1 fused RMSNorm + scan pass-1 — REGISTER-BURST A (the gemm2 mechanism).
// Little's-law diagnosis (r12 PMC: 722 GB/s latency-capped, FETCH=dur):
// all prior gemm1s kept <=12 loads in flight/wave -> ~700 GB/s stream cap.
// gemm2 streams its big operand via 64 independent per-thread register loads
// (wave-deep outstanding queue) and keeps its K-loop on L2-hot weights only.
// Clone that: K=1024 in 4 quarters; per quarter burst 16x dwordx4 of fp32 u
// into regs -> cvt f16 + sumsq -> swizzled ds_write to resident As (32 KB)
// -> 8-step K-loop staging only Bt (1 MB, L2-hot).  LDS 48 KB -> 3 blocks/CU
// (neighbors' MFMA covers each block's burst drain).  rs at epilogue.
// ---------------------------------------------------------------------------
__global__ __launch_bounds__(256)
void gemm1_rms_chfin(const float* __restrict__ U, const f16* __restrict__ Bt,
                     f16* __restrict__ up, float* __restrict__ chlast,
                     const float* __restrict__ dt, const float* __restrict__ Avec) {
    constexpr int K = I_DIM, N = S_DIM;   // K=1024: 4 quarters x 256
    __shared__ f16 As[64 * 256];          // 32 KB resident quarter
    __shared__ f16 Bs[2][128 * 32];       // 16 KB
    __shared__ float rsbuf[64];
    const int t = threadIdx.x;

    // XCD swizzle (512 = 8*64): 4 consecutive logical bids share an A panel
    int bid = blockIdx.x;
    bid = (bid & 7) * 64 + (bid >> 3);
    const int n0 = (bid & 3) * 128;       // 4 n-blocks
    const int m0 = (bid >> 2) * 64;       // 128 m-blocks
    const int wid = t >> 6, lane = t & 63;
    const int wn = wid * 32, lr = lane & 15, kg = lane >> 4;

    // A burst: thread owns row r=t>>2, f32 cols (t&3)*64..+63 of each quarter
    const int ar_row = t >> 2;
    const float* aptr = U + (size_t)(m0 + ar_row) * K + (t & 3) * 64;
    const int r7 = ar_row & 7;            // write-side XOR term
    const int gchk0 = (t & 3) * 8;        // first global chunk this thread owns

    // B staging (r12-proven): source chunk swizzle + read chunk swizzle
    const int swch = (t & 3) ^ ((t >> 3) & 3);
    const f16* bptr = Bt + (size_t)(n0 + (t >> 2)) * K + swch * 8;
    const int rchunkB = (kg ^ ((lr >> 1) & 3)) * 8;
    const int axor = lr & 7;              // A read-side XOR (row&7 == lr&7)

    auto stageB = [&](int kt, int slot) {   // kt = global k-step 0..31
        load16_lds(bptr + kt * 32, &Bs[slot][t * 8]);
        load16_lds(bptr + (size_t)64 * K + kt * 32, &Bs[slot][2048 + t * 8]);
    };

    float ss = 0.f;
    f32x4 acc[4][2];
    #pragma unroll
    for (int i = 0; i < 4; ++i)
        #pragma unroll
        for (int j = 0; j < 2; ++j) acc[i][j] = (f32x4){0.f, 0.f, 0.f, 0.f};

    #pragma unroll
    for (int q = 0; q < 4; ++q) {
        // ---- register burst: 16 independent dwordx4 (wave-deep queue) ----
        float4 ar[16];
        #pragma unroll
        for (int j = 0; j < 16; ++j)
            ar[j] = *(const float4*)(aptr + q * 256 + j * 4);
        stageB(q * 8, 0);                       // B(first step) rides behind
        asm volatile("s_waitcnt vmcnt(2)");     // burst retired; B0 in flight

        // ---- cvt f16 + sumsq + swizzled ds_write (8 chunks of 8 f16) ----
        #pragma unroll
        for (int c = 0; c < 8; ++c) {
            const float4 a0 = ar[2 * c], a1 = ar[2 * c + 1];
            ss += a0.x * a0.x + a0.y * a0.y + a0.z * a0.z + a0.w * a0.w
                + a1.x * a1.x + a1.y * a1.y + a1.z * a1.z + a1.w * a1.w;
            f16x8 h = { (_Float16)a0.x, (_Float16)a0.y, (_Float16)a0.z, (_Float16)a0.w,
                        (_Float16)a1.x, (_Float16)a1.y, (_Float16)a1.z, (_Float16)a1.w };
            const int ldc = (gchk0 + c) ^ r7;   // LDS chunk (XOR-swizzled)
            *(f16x8*)&As[ar_row * 256 + ldc * 8] = h;
        }
        asm volatile("s_waitcnt lgkmcnt(0)");   // ds_writes visible
        __builtin_amdgcn_s_barrier();           // As(q) + nothing else needed

        // ---- 8-step K-loop: As resident, Bt (L2-hot) double-buffered ----
        #pragma unroll
        for (int ks = 0; ks < 8; ++ks) {
            const int cur = ks & 1;
            if (ks < 7) {
                stageB(q * 8 + ks + 1, cur ^ 1);
                asm volatile("s_waitcnt vmcnt(2)");  // B[ks] done; B[ks+1] flying
            } else {
                asm volatile("s_waitcnt vmcnt(0)");  // quarter drain
            }
            __builtin_amdgcn_s_barrier();
            __builtin_amdgcn_sched_barrier(0);

            f16x8 af[4], bf[2];
            #pragma unroll
            for (int m = 0; m < 4; ++m)
                af[m] = *(const f16x8*)&As[(m * 16 + lr) * 256 + (((ks * 4 + kg) ^ axor) * 8)];
            #pragma unroll
            for (int n = 0; n < 2; ++n)
                bf[n] = *(const f16x8*)&Bs[cur][(wn + n * 16 + lr) * 32 + rchunkB];
            __builtin_amdgcn_s_setprio(1);
            #pragma unroll
            for (int m = 0; m < 4; ++m)
                #pragma unroll
                for (int n = 0; n < 2; ++n)
                    acc[m][n] = __builtin_amdgcn_mfma_f32_16x16x32_f16(af[m], bf[n], acc[m][n], 0, 0, 0);
            __builtin_amdgcn_s_setprio(0);
            __builtin_amdgcn_s_barrier();   // reads done: safe restage / re-burst
        }
    }

    // rs per row: 4 threads share a row -> xor-reduce sumsq
    ss += __shfl_xor(ss, 1, 64);
    ss += __shfl_xor(ss, 2, 64);
    if ((t & 3) == 0) rsbuf[t >> 2] = rsqrtf(ss * (1.0f / K) + EPSF);
    __syncthreads();

    // epilogue: up = rs*acc (f16) + fused chunk-final (fp32)
    // C/D layout: col = lane&15, row = (lane>>4)*4 + reg
    const int cb = m0 >> 11;               // batch
    const int cc = (m0 >> 6) & (NCH - 1);  // chunk
    #pragma unroll
    for (int n = 0; n < 2; ++n) {
        const int col = n0 + wn + n * 16 + lr;
        const float dts = 1.0f / (1.0f + expf(-dt[col]));
        const float e = dts * fabsf(Avec[col]);
        const float ainv = expf(e);        // a^-1
        float partial = 0.f;
        #pragma unroll
        for (int m = 0; m < 4; ++m) {
            const int row = m * 16 + kg * 4;
            f32x4 rs4 = *(const f32x4*)&rsbuf[row];
            float wgt = expf(-e * (float)(63 - row));   // a^(63-row)
            #pragma unroll
            for (int j = 0; j < 4; ++j) {
                const float val = rs4[j] * acc[m][n][j];
                up[(size_t)(m0 + row + j) * N + col] = (_Float16)val;
                partial = fmaf(wgt, val, partial);
                wgt *= ainv;
            }
        }
        partial += __shfl_xor(partial, 16, 64);
        partial += __shfl_xor(partial, 32, 64);
        if (kg == 0)
            chlast[(size_t)(cb * NCH + cc) * S_DIM + col] = partial;
    }
}

// ---------------------------------------------------------------------------
// GEMM2 fused with scan pass-2 (r12-proven, ~10 us).  LDS exactly 80 KB.
// ---------------------------------------------------------------------------
__global__ __launch_bounds__(256)
void gemm2_scan(const f16* __restrict__ upb, const float* __restrict__ chlast,
                const f16* __restrict__ Ct, const float* __restrict__ Dvec,
                const float* __restrict__ dt, const float* __restrict__ Avec,
                float* __restrict__ y, float* __restrict__ xlast) {
    constexpr int K = S_DIM, N = O_DIM, NK = K / 32;   // 16 k-steps
    __shared__ __align__(16) unsigned char As[64 * 1024];   // 64 KB x-tile
    __shared__ f16 Bs[2][128 * 32];                         // 16 KB
    const int t = threadIdx.x;

    int bid = blockIdx.x;                 // grid = 1024
    bid = (bid & 7) * 128 + (bid >> 3);
    const int n0 = (bid & 7) * 128;       // 8 n-blocks
    const int m0 = (bid >> 3) * 64;       // 128 m-blocks (= b*32 + chunk)
    const int wid = t >> 6, lane = t & 63;
    const int wn = wid * 32, lr = lane & 15, kg = lane >> 4;

    // stage B(0) early (pre-swizzled source)
    const int srcswz = ((t & 3) ^ ((t >> 3) & 3)) * 8;
    const f16* bptr = Ct + (size_t)(n0 + (t >> 2)) * K + srcswz;
    auto stageB = [&](int kt, int slot) {
        load16_lds(bptr + kt * 32, &Bs[slot][t * 8]);
        load16_lds(bptr + (size_t)64 * K + kt * 32, &Bs[slot][2048 + t * 8]);
    };
    stageB(0, 0);
    const int rchunk = (kg ^ ((lr >> 1) & 3)) * 8;

    // ---- issue up-chunk loads FIRST (64 independent dwords in flight) ----
    const unsigned* up32 = (const unsigned*)upb;
    const size_t ub = (size_t)m0 * 256 + t;
    unsigned v[CL];
    #pragma unroll
    for (int j = 0; j < CL; ++j) v[j] = up32[ub + (size_t)j * 256];

    // ---- carry prefix over chunk finals (overlaps up-load flight) ----
    const int cc = (m0 >> 6) & (NCH - 1);
    const int cb = m0 >> 11;
    const int s0 = 2 * t;
    const float dts0 = 1.0f / (1.0f + expf(-dt[s0]));
    const float dts1 = 1.0f / (1.0f + expf(-dt[s0 + 1]));
    const float ab0 = fabsf(Avec[s0]), ab1 = fabsf(Avec[s0 + 1]);
    const float g0 = expf(-dts0 * ab0);
    const float g1 = expf(-dts1 * ab1);
    const float gCL0 = expf(-dts0 * ab0 * (float)CL);
    const float gCL1 = expf(-dts1 * ab1 * (float)CL);
    const float2* ch = (const float2*)chlast;
    float cy0 = 0.f, cy1 = 0.f;
    {
        int j = 0;
        for (; j + 4 <= cc; j += 4) {
            float2 f0 = ch[(size_t)(cb * NCH + j + 0) * 256 + t];
            float2 f1 = ch[(size_t)(cb * NCH + j + 1) * 256 + t];
            float2 f2 = ch[(size_t)(cb * NCH + j + 2) * 256 + t];
            float2 f3 = ch[(size_t)(cb * NCH + j + 3) * 256 + t];
            cy0 = fmaf(gCL0, cy0, f0.x); cy1 = fmaf(gCL1, cy1, f0.y);
            cy0 = fmaf(gCL0, cy0, f1.x); cy1 = fmaf(gCL1, cy1, f1.y);
            cy0 = fmaf(gCL0, cy0, f2.x); cy1 = fmaf(gCL1, cy1, f2.y);
            cy0 = fmaf(gCL0, cy0, f3.x); cy1 = fmaf(gCL1, cy1, f3.y);
        }
        for (; j < cc; ++j) {
            float2 f = ch[(size_t)(cb * NCH + j) * 256 + t];
            cy0 = fmaf(gCL0, cy0, f.x);
            cy1 = fmaf(gCL1, cy1, f.y);
        }
    }

    // ---- scan + swizzled LDS write ----
    float x0 = cy0, x1 = cy1;
    #pragma unroll
    for (int j = 0; j < CL; ++j) {
        f16x2 h = __builtin_bit_cast(f16x2, v[j]);
        x0 = fmaf(g0, x0, (float)h.x);
        x1 = fmaf(g1, x1, (float)h.y);
        f16x2 o; o.x = (_Float16)x0; o.y = (_Float16)x1;
        v[j] = __builtin_bit_cast(unsigned, o);
    }
    #pragma unroll
    for (int j = 0; j < CL; ++j)
        *(unsigned*)&As[j * 1024 + ((t * 4) ^ ((j & 7) << 4))] = v[j];
    if (cc == NCH - 1)
        ((float2*)xlast)[cb * 256 + t] = make_float2(x0, x1);   // dup across n-blocks, same value
    __syncthreads();   // one-time full drain: scan ds_writes + B(0) staging

    // ---- K-loop: A resident in LDS, B double-buffered, counted vmcnt ----
    f32x4 acc[4][2];
    #pragma unroll
    for (int i = 0; i < 4; ++i)
        #pragma unroll
        for (int j = 0; j < 2; ++j) acc[i][j] = (f32x4){0.f, 0.f, 0.f, 0.f};

    const int swz = (lr & 7) << 4;        // row&7 == lr&7 for row = m*16+lr
    for (int kt = 0; kt < NK; ++kt) {
        const int cur = kt & 1;
        if (kt + 1 < NK) {
            stageB(kt + 1, cur ^ 1);
            asm volatile("s_waitcnt vmcnt(2)");   // B[kt] done; B[kt+1] in flight
        } else {
            asm volatile("s_waitcnt vmcnt(0)");
        }
        __builtin_amdgcn_s_barrier();
        __builtin_amdgcn_sched_barrier(0);

        f16x8 af[4], bf[2];
        #pragma unroll
        for (int m = 0; m < 4; ++m)
            af[m] = *(const f16x8*)&As[(m * 16 + lr) * 1024 + ((kt * 64 + kg * 16) ^ swz)];
        #pragma unroll
        for (int n = 0; n < 2; ++n)
            bf[n] = *(const f16x8*)&Bs[cur][(wn + n * 16 + lr) * 32 + rchunk];
        __builtin_amdgcn_s_setprio(1);
        #pragma unroll
        for (int m = 0; m < 4; ++m)
            #pragma unroll
            for (int n = 0; n < 2; ++n)
                acc[m][n] = __builtin_amdgcn_mfma_f32_16x16x32_f16(af[m], bf[n], acc[m][n], 0, 0, 0);
        __builtin_amdgcn_s_setprio(0);
        __builtin_amdgcn_s_barrier();    // Bs[cur] reads done before restage
    }

    // epilogue: y = acc + D
    #pragma unroll
    for (int n = 0; n < 2; ++n) {
        const int col = n0 + wn + n * 16 + lr;
        const float dv = Dvec[col];
        #pragma unroll
        for (int m = 0; m < 4; ++m) {
            const int row = m0 + m * 16 + kg * 4;
            #pragma unroll
            for (int j = 0; j < 4; ++j)
                y[(size_t)(row + j) * N + col] = acc[m][n][j] + dv;
        }
    }
}

// ---------------------------------------------------------------------------
extern "C" void kernel_launch(void* const* d_in, const int* in_sizes, int n_in,
                              void* d_out, int out_size, void* d_ws, size_t ws_size,
                              hipStream_t stream) {
    const float* u    = (const float*)d_in[0];   // [B,T,I]
    const float* dt   = (const float*)d_in[1];   // [S]
    const float* Avec = (const float*)d_in[2];   // [S]
    const float* Bmat = (const float*)d_in[3];   // [I,S]
    const float* Cmat = (const float*)d_in[4];   // [S,O]
    const float* Dvec = (const float*)d_in[5];   // [O]
    const float* nw   = (const float*)d_in[6];   // [I]

    float* y     = (float*)d_out;                      // [B,T,O] fp32
    float* xlast = y + (size_t)M_ROWS * O_DIM;         // [B,S]   fp32

    // workspace (~11 MB)
    char* w = (char*)d_ws;
    f16*            up16   = (f16*)(w);                          // [8192,512] f16
    unsigned short* Bt16   = (unsigned short*)(w + 8388608);     // [512,1024] f16 (dts,nw folded)
    unsigned short* Ct16   = (unsigned short*)(w + 9437184);     // [1024,512] f16
    float*          chlast = (float*)(w + 10485760);             // [B,NCH,S]  fp32

    // 1. weight transposes
    prep_w<<<1024, 256, 0, stream>>>(Bmat, dt, nw, Bt16, Cmat, Ct16);

    // 2. GEMM1 (+rmsnorm +chunk finals): up16 = f16(u)@Bt * rs, chlast
    gemm1_rms_chfin<<<512, 256, 0, stream>>>(u, (const f16*)Bt16, up16, chlast, dt, Avec);

    // 3. GEMM2 (+carry +scan): y, xlast
    gemm2_scan<<<1024, 256, 0, stream>>>(up16, chlast, (const f16*)Ct16, Dvec,
                                         dt, Avec, y, xlast);
}